// Round 12
// baseline (109.607 us; speedup 1.0000x reference)
//
#include <hip/hip_runtime.h>
#include <stdint.h>

typedef __bf16 bf16;
typedef __attribute__((ext_vector_type(4))) __bf16 bf16x4;
typedef __attribute__((ext_vector_type(8))) __bf16 bf16x8;
typedef __attribute__((ext_vector_type(4))) float f32x4;
typedef __attribute__((ext_vector_type(4))) unsigned int u32x4;

#define W_ 160
#define H_ 96
#define C_ 128
#define B_ 16
#define HW_ (H_ * W_)            // 15360
#define NXT 10                   // 160/16
#define NYB4 24                  // 96/4: 4-row y-bands
#define NBLK (B_ * NYB4 * NXT)   // 3840 = 8*480
#define SLICEB 10240             // in2t bytes per (y,ck) slice: 160x * 4 granules * 16B
#define YB 40960                 // per (b,y): 4 slices
#define ROWSB 2048               // LDS bytes per staged row: 32 xl-slots * 64B
#define CHB (12 * ROWSB)         // 24576 B per chunk (12 halo rows)
#define WSSTR 1312               // floats per wave epilogue region

__device__ float g_zero[16];     // zero-initialized; never written

__device__ __forceinline__ void g2l16(const void* g, void* l) {
    __builtin_amdgcn_global_load_lds(
        (const __attribute__((address_space(1))) void*)g,
        (__attribute__((address_space(3))) void*)l, 16, 0, 0);
}

// ===== pass 1: in2 [B][C][H][W] f32 -> in2t [b][y][ck][x*4+(g^((x>>1)&3))] bf16 granules (x 1/128)
__global__ __launch_bounds__(256) void t2_kernel(const float* __restrict__ in2,
                                                 char* __restrict__ o) {
    __shared__ __align__(16) char T[40960];         // [x][pos-swizzled 16 granules]
    const int L   = blockIdx.x;                     // b*H_ + y
    const int tid = threadIdx.x;
    const float* src = in2 + (size_t)(L / H_) * C_ * HW_ + (size_t)(L % H_) * W_;
    char* dst = o + (size_t)L * YB;
    const float SC = 1.0f / 128.0f;                 // exact fold of 1/(K*K*C)
#pragma unroll
    for (int rd = 0; rd < 5; ++rd) {                // load + c->x transpose (r8-proven)
        const int s  = rd * 256 + tid;              // 0..1279 = 32 cq x 40 x4
        const int cq = s / 40;
        const int x4 = s - cq * 40;
        const float* p = src + (size_t)(4 * cq) * HW_ + 4 * x4;
        const float4 v0 = *(const float4*)(p);
        const float4 v1 = *(const float4*)(p + HW_);
        const float4 v2 = *(const float4*)(p + 2 * HW_);
        const float4 v3 = *(const float4*)(p + 3 * HW_);
        const int oq = cq >> 1, half = cq & 1;
#pragma unroll
        for (int xj = 0; xj < 4; ++xj) {
            const int x   = 4 * x4 + xj;
            const int pos = oq ^ ((x >> 2) & 15);   // T's own bank swizzle
            bf16x4 pk;
            pk[0] = (bf16)(((const float*)&v0)[xj] * SC);
            pk[1] = (bf16)(((const float*)&v1)[xj] * SC);
            pk[2] = (bf16)(((const float*)&v2)[xj] * SC);
            pk[3] = (bf16)(((const float*)&v3)[xj] * SC);
            *(bf16x4*)(T + x * 256 + pos * 16 + half * 8) = pk;
        }
    }
    __syncthreads();
#pragma unroll
    for (int wr = 0; wr < 10; ++wr) {               // write in [ck][x][gsw] granule order
        const int s2  = wr * 256 + tid;             // 0..2559
        const int ck  = s2 / 640;
        const int r   = s2 - ck * 640;
        const int x   = r >> 2;
        const int gsw = r & 3;
        const int gg  = gsw ^ ((x >> 1) & 3);       // octet stored at this granule
        const int oo  = ck * 4 + gg;
        const int pos = oo ^ ((x >> 2) & 15);
        const u32x4 v = *(const u32x4*)(T + x * 256 + pos * 16);
        *(u32x4*)(dst + (size_t)s2 * 16) = v;       // fully coalesced
    }
}

// ===== pass 2: counted-vmcnt 3-buffer pipeline; 4-wave block = 4 y-rows
__global__ __launch_bounds__(256, 2) void corr_mfma5(const float* __restrict__ in1,
                                                     const char* __restrict__ in2t,
                                                     float* __restrict__ out) {
    __shared__ __align__(16) char Bsm[3 * CHB];     // 73728 B; reused for epilogue

    const int L   = ((int)blockIdx.x & 7) * (NBLK / 8) + ((int)blockIdx.x >> 3);
    const int b   = L / (NYB4 * NXT);
    const int rem = L % (NYB4 * NXT);
    const int yb  = rem / NXT;
    const int xt  = rem % NXT;
    const int x0  = xt * 16, y0 = yb * 4;

    const int tid  = threadIdx.x;
    const int wv   = __builtin_amdgcn_readfirstlane(tid >> 6);  // wave 0..3 -> y row
    const int lane = tid & 63;
    const int n    = lane & 15;          // frag col (A row m / B col)
    const int g    = lane >> 4;          // k-octet
    const int y    = y0 + wv;

    const char* i2tb = in2t + (size_t)b * (H_ * YB);

    // ---- stage descriptors: 6 rounds x 256 thr = 1536 slots = 12 rows x 128 ----
    const char* srow[6];
    bool stgv[6];
#pragma unroll
    for (int rd = 0; rd < 6; ++rd) {
        const int s   = rd * 256 + tid;
        const int row = s >> 7;                     // 0..11
        const int sl  = s & 127;                    // granule within row (>=96: zero pad)
        const int gy  = y0 - 4 + row;
        const int x   = x0 - 4 + (sl >> 2);
        stgv[rd] = (sl < 96) && ((unsigned)gy < (unsigned)H_) && ((unsigned)x < (unsigned)W_);
        const int gy_c = min(max(gy, 0), H_ - 1);
        const int ofs  = max((x0 - 4) * 64 + sl * 16, 0);
        srow[rd] = i2tb + (size_t)gy_c * YB + ofs;  // + ck*SLICEB at stage time
    }

    // ---- A fragments FIRST, fully retired before any staging load ----
    const float* abase = in1 + (size_t)b * C_ * HW_ + (size_t)y * W_ + (x0 + n);
    float a_raw[32];
#pragma unroll
    for (int i = 0; i < 32; ++i)
        a_raw[i] = abase[(size_t)((i >> 3) * 32 + g * 8 + (i & 7)) * HW_];
    bf16x8 afrag[4];
#pragma unroll
    for (int ck = 0; ck < 4; ++ck)
#pragma unroll
        for (int j = 0; j < 8; ++j)
            afrag[ck][j] = (bf16)a_raw[ck * 8 + j];
    asm volatile("s_waitcnt vmcnt(0)" ::: "memory");   // only staging loads remain in vmcnt
    __builtin_amdgcn_sched_barrier(0);

    // ---- B-frag read offsets; swizzle term ((x0-4+xl)>>1)&3 == ((xl+12)>>1)&3 ----
    int rboff[2];
#pragma unroll
    for (int t = 0; t < 2; ++t) {
        const int xl = n + 16 * t;
        const int sw = g ^ (((xl + 12) >> 1) & 3);
        rboff[t] = (xl * 4 + sw) * 16;
    }

    f32x4 acc[9][2];
#pragma unroll
    for (int dyi = 0; dyi < 9; ++dyi)
#pragma unroll
        for (int t = 0; t < 2; ++t)
            acc[dyi][t] = (f32x4){0.f, 0.f, 0.f, 0.f};

    // Full-wave exec; invalid lanes pull 16B zeros from g_zero. Exactly 6 loads/STAGE.
#define STAGE(CK, DST)                                                        \
    {                                                                         \
        _Pragma("unroll")                                                     \
        for (int rd = 0; rd < 6; ++rd)                                        \
            g2l16(stgv[rd] ? (const void*)(srow[rd] + (CK) * SLICEB)          \
                           : (const void*)g_zero,                             \
                  (void*)((DST) + rd * 4096 + tid * 16));                     \
    }
    // Counted wait: per wave only staging g2l16 are outstanding at these points.
#define WAITB(N)                                                              \
    {                                                                         \
        asm volatile("s_waitcnt vmcnt(" #N ")" ::: "memory");                 \
        __builtin_amdgcn_s_barrier();                                         \
        __builtin_amdgcn_sched_barrier(0);                                    \
    }
#define COMPUTE(CK, BUF)                                                      \
    {                                                                         \
        _Pragma("unroll")                                                     \
        for (int dyi = 0; dyi < 9; ++dyi) {                                   \
            const int rowoff = (wv + dyi) * ROWSB;                            \
            _Pragma("unroll")                                                 \
            for (int t = 0; t < 2; ++t) {                                     \
                const bf16x8 bfrag =                                          \
                    *(const bf16x8*)((BUF) + rowoff + rboff[t]);              \
                acc[dyi][t] = __builtin_amdgcn_mfma_f32_16x16x32_bf16(        \
                    afrag[CK], bfrag, acc[dyi][t], 0, 0, 0);                  \
            }                                                                 \
        }                                                                     \
    }

    STAGE(0, Bsm);                 // 6  in flight
    STAGE(1, Bsm + CHB);           // 12
    STAGE(2, Bsm + 2 * CHB);       // 18
    WAITB(12);                     // chunk0 landed (1,2 still flying)
    COMPUTE(0, Bsm);
    WAITB(6);                      // chunk1 landed (2 flying); all waves done reading B0
    STAGE(3, Bsm);                 // overwrite B0: safe post-barrier
    COMPUTE(1, Bsm + CHB);
    WAITB(6);                      // chunk2 landed (3 flying)
    COMPUTE(2, Bsm + 2 * CHB);
    WAITB(0);                      // chunk3 landed
    COMPUTE(3, Bsm);
#undef STAGE
#undef WAITB
#undef COMPUTE

    __syncthreads();               // all LDS reads done before epilogue reuse

    // ---- epilogue (r7-proven): per-wave LDS transpose -> coalesced stores ----
    float* wsw = (float*)Bsm + wv * WSSTR;          // 20992 B <= 73728
#pragma unroll
    for (int dyi = 0; dyi < 9; ++dyi)
#pragma unroll
        for (int t = 0; t < 2; ++t)
#pragma unroll
            for (int rr = 0; rr < 4; ++rr) {
                const int m = 4 * g + rr;
                const int d = n + 16 * t - m;
                if ((unsigned)d <= 8u)
                    wsw[(dyi * 9 + d) * 16 + m] = acc[dyi][t][rr];
            }
    __syncthreads();

    const int mm = lane & 15, rg = lane >> 4;
    const size_t ob = (size_t)(b * 81) * HW_ + (size_t)y * W_ + (x0 + mm);
#pragma unroll
    for (int q4 = 0; q4 < 20; ++q4) {
        const int rho = q4 * 4 + rg;
        out[ob + (size_t)rho * HW_] = wsw[rho * 16 + mm];
    }
    if (rg == 0)
        out[ob + (size_t)80 * HW_] = wsw[80 * 16 + mm];
}

extern "C" void kernel_launch(void* const* d_in, const int* in_sizes, int n_in,
                              void* d_out, int out_size, void* d_ws, size_t ws_size,
                              hipStream_t stream) {
    const float* in1 = (const float*)d_in[0];
    const float* in2 = (const float*)d_in[1];
    float* out = (float*)d_out;
    (void)in_sizes; (void)n_in; (void)out_size; (void)ws_size;
    char* in2t = (char*)d_ws;            // 62.9 MB, fits (r8/r11-verified)
    hipLaunchKernelGGL(t2_kernel, dim3(B_ * H_), dim3(256), 0, stream, in2, in2t);
    hipLaunchKernelGGL(corr_mfma5, dim3(NBLK), dim3(256), 0, stream, in1, in2t, out);
}

// Round 13
// 101.040 us; speedup vs baseline: 1.0848x; 1.0848x over previous
//
#include <hip/hip_runtime.h>
#include <stdint.h>

typedef __bf16 bf16;
typedef __attribute__((ext_vector_type(4))) __bf16 bf16x4;
typedef __attribute__((ext_vector_type(8))) __bf16 bf16x8;
typedef __attribute__((ext_vector_type(4))) float f32x4;
typedef __attribute__((ext_vector_type(4))) unsigned int u32x4;

#define W_ 160
#define H_ 96
#define C_ 128
#define B_ 16
#define HW_ (H_ * W_)            // 15360
#define NXT 10                   // 160/16
#define NYB8 12                  // 96/8: 8-row y-bands
#define NBLK (B_ * NYB8 * NXT)   // 1920 = 8*240
#define SLICEB 10240             // in2t bytes per (y,ck) slice: 160x * 4 granules * 16B
#define YB 40960                 // per (b,y): 4 slices
#define ROWSB 1536               // LDS bytes per staged row: 24 xl * 4 granules * 16B
#define CHB (16 * ROWSB)         // 24576 B per chunk (16 halo rows)
#define WSSTR 1312               // floats per wave epilogue region

__device__ float g_zero[16];     // zero-initialized; never written

__device__ __forceinline__ void g2l16(const void* g, void* l) {
    __builtin_amdgcn_global_load_lds(
        (const __attribute__((address_space(1))) void*)g,
        (__attribute__((address_space(3))) void*)l, 16, 0, 0);
}

// ===== pass 1 (r11-verified): in2 [B][C][H][W] f32 -> in2t granules [b][y][ck][x*4+(g^((x>>1)&3))]
__global__ __launch_bounds__(256) void t2_kernel(const float* __restrict__ in2,
                                                 char* __restrict__ o) {
    __shared__ __align__(16) char T[40960];
    const int L   = blockIdx.x;                     // b*H_ + y
    const int tid = threadIdx.x;
    const float* src = in2 + (size_t)(L / H_) * C_ * HW_ + (size_t)(L % H_) * W_;
    char* dst = o + (size_t)L * YB;
    const float SC = 1.0f / 128.0f;                 // exact fold of 1/(K*K*C)
#pragma unroll
    for (int rd = 0; rd < 5; ++rd) {
        const int s  = rd * 256 + tid;              // 0..1279 = 32 cq x 40 x4
        const int cq = s / 40;
        const int x4 = s - cq * 40;
        const float* p = src + (size_t)(4 * cq) * HW_ + 4 * x4;
        const float4 v0 = *(const float4*)(p);
        const float4 v1 = *(const float4*)(p + HW_);
        const float4 v2 = *(const float4*)(p + 2 * HW_);
        const float4 v3 = *(const float4*)(p + 3 * HW_);
        const int oq = cq >> 1, half = cq & 1;
#pragma unroll
        for (int xj = 0; xj < 4; ++xj) {
            const int x   = 4 * x4 + xj;
            const int pos = oq ^ ((x >> 2) & 15);
            bf16x4 pk;
            pk[0] = (bf16)(((const float*)&v0)[xj] * SC);
            pk[1] = (bf16)(((const float*)&v1)[xj] * SC);
            pk[2] = (bf16)(((const float*)&v2)[xj] * SC);
            pk[3] = (bf16)(((const float*)&v3)[xj] * SC);
            *(bf16x4*)(T + x * 256 + pos * 16 + half * 8) = pk;
        }
    }
    __syncthreads();
#pragma unroll
    for (int wr = 0; wr < 10; ++wr) {
        const int s2  = wr * 256 + tid;
        const int ck  = s2 / 640;
        const int r   = s2 - ck * 640;
        const int x   = r >> 2;
        const int gsw = r & 3;
        const int gg  = gsw ^ ((x >> 1) & 3);
        const int oo  = ck * 4 + gg;
        const int pos = oo ^ ((x >> 2) & 15);
        const u32x4 v = *(const u32x4*)(T + x * 256 + pos * 16);
        *(u32x4*)(dst + (size_t)s2 * 16) = v;
    }
}

// ===== pass 2: 8-wave y-band-8 blocks, counted-vmcnt dbuf pipeline, reg-dieted
__global__ __launch_bounds__(512, 4) void corr_mfma6(const float* __restrict__ in1,
                                                     const char* __restrict__ in2t,
                                                     float* __restrict__ out) {
    __shared__ __align__(16) char Bsm[2 * CHB + 512];   // 49664 B (+pad for t=1 overread)

    const int L   = ((int)blockIdx.x & 7) * (NBLK / 8) + ((int)blockIdx.x >> 3);
    const int b   = L / (NYB8 * NXT);
    const int rem = L % (NYB8 * NXT);
    const int yb  = rem / NXT;
    const int xt  = rem % NXT;
    const int x0  = xt * 16, y0 = yb * 8;

    const int tid  = threadIdx.x;
    const int wv   = __builtin_amdgcn_readfirstlane(tid >> 6);  // wave 0..7 -> y row
    const int lane = tid & 63;
    const int n    = lane & 15;          // frag col (A row m / B col)
    const int g    = lane >> 4;          // k-octet
    const int y    = y0 + wv;

    const char* i2tb = in2t + (size_t)b * (H_ * YB);

    // ---- A fragments: per-ck batches of 8 (register diet), retired before staging ----
    const float* abase = in1 + (size_t)b * C_ * HW_ + (size_t)y * W_ + (x0 + n);
    bf16x8 afrag[4];
#pragma unroll
    for (int ck = 0; ck < 4; ++ck) {
        float ar[8];
#pragma unroll
        for (int j = 0; j < 8; ++j)
            ar[j] = abase[(size_t)(ck * 32 + g * 8 + j) * HW_];
#pragma unroll
        for (int j = 0; j < 8; ++j)
            afrag[ck][j] = (bf16)ar[j];
    }
    asm volatile("s_waitcnt vmcnt(0)" ::: "memory");   // vmcnt now tracks staging only
    __builtin_amdgcn_sched_barrier(0);

    // ---- staging decode: 3 rounds x 512 thr = 1536 slots = 16 rows x 96 granules ----
    unsigned soff[3];
    bool     sv[3];
#pragma unroll
    for (int rd = 0; rd < 3; ++rd) {
        const int slot = rd * 512 + tid;
        const int row  = slot / 96;
        const int sl   = slot - row * 96;
        const int gy   = y0 - 4 + row;
        const int x    = x0 - 4 + (sl >> 2);
        sv[rd] = ((unsigned)gy < (unsigned)H_) && ((unsigned)x < (unsigned)W_);
        const int gy_c = min(max(gy, 0), H_ - 1);
        const int ofs  = max((x0 - 4) * 64 + sl * 16, 0);
        soff[rd] = (unsigned)(gy_c * YB + ofs);
    }

    // ---- B-frag read offsets: granule (xl*4 + (g ^ (((x0-4+xl)>>1)&3))) * 16 ----
    int rboff[2];
#pragma unroll
    for (int t = 0; t < 2; ++t) {
        const int xl = n + 16 * t;
        const int sw = g ^ (((xl + 12) >> 1) & 3);   // == ((x0-4+xl)>>1)&3 for x0%16==0
        rboff[t] = (xl * 4 + sw) * 16;
    }

    f32x4 acc[9][2];
#pragma unroll
    for (int dyi = 0; dyi < 9; ++dyi)
#pragma unroll
        for (int t = 0; t < 2; ++t)
            acc[dyi][t] = (f32x4){0.f, 0.f, 0.f, 0.f};

    // Full-wave exec; invalid lanes pull 16B zeros from g_zero. Exactly 3 loads/STAGE/wave.
#define STAGE(CK, DST)                                                        \
    {                                                                         \
        const char* bck = i2tb + (CK) * SLICEB;                               \
        _Pragma("unroll")                                                     \
        for (int rd = 0; rd < 3; ++rd)                                        \
            g2l16(sv[rd] ? (const void*)(bck + soff[rd])                      \
                         : (const void*)g_zero,                               \
                  (void*)((DST) + (rd * 512 + tid) * 16));                    \
    }
#define WAITB(N)                                                              \
    {                                                                         \
        asm volatile("s_waitcnt vmcnt(" #N ")" ::: "memory");                 \
        __builtin_amdgcn_s_barrier();                                         \
        __builtin_amdgcn_sched_barrier(0);                                    \
    }
#define RBAR                                                                  \
    {                                                                         \
        asm volatile("s_waitcnt lgkmcnt(0)" ::: "memory");                    \
        __builtin_amdgcn_s_barrier();                                         \
        __builtin_amdgcn_sched_barrier(0);                                    \
    }
#define COMPUTE(CK, BUF)                                                      \
    {                                                                         \
        _Pragma("unroll")                                                     \
        for (int dyi = 0; dyi < 9; ++dyi) {                                   \
            const int rowoff = (wv + dyi) * ROWSB;                            \
            _Pragma("unroll")                                                 \
            for (int t = 0; t < 2; ++t) {                                     \
                const bf16x8 bfrag =                                          \
                    *(const bf16x8*)((BUF) + rowoff + rboff[t]);              \
                acc[dyi][t] = __builtin_amdgcn_mfma_f32_16x16x32_bf16(        \
                    afrag[CK], bfrag, acc[dyi][t], 0, 0, 0);                  \
            }                                                                 \
        }                                                                     \
    }

    STAGE(0, Bsm);                 // 3 in flight
    STAGE(1, Bsm + CHB);           // 6
    WAITB(3);                      // chunk0 landed everywhere (barrier: all waves too)
    COMPUTE(0, Bsm);
    RBAR;                          // all waves done reading B0
    STAGE(2, Bsm);                 // 3(c1) + 3(c2) = 6 in flight
    WAITB(3);                      // chunk1 landed
    COMPUTE(1, Bsm + CHB);
    RBAR;                          // all waves done reading B1
    STAGE(3, Bsm + CHB);           // 3(c2) + 3(c3) = 6
    WAITB(3);                      // chunk2 landed
    COMPUTE(2, Bsm);
    WAITB(0);                      // chunk3 landed
    COMPUTE(3, Bsm + CHB);
#undef STAGE
#undef WAITB
#undef RBAR
#undef COMPUTE

    __syncthreads();               // full drain before LDS reuse

    // ---- epilogue (r7-verified): per-wave LDS transpose -> coalesced stores ----
    float* wsw = (float*)Bsm + wv * WSSTR;          // 8*5248 = 41984 B <= 49664
#pragma unroll
    for (int dyi = 0; dyi < 9; ++dyi)
#pragma unroll
        for (int t = 0; t < 2; ++t)
#pragma unroll
            for (int rr = 0; rr < 4; ++rr) {
                const int m = 4 * g + rr;
                const int d = n + 16 * t - m;
                if ((unsigned)d <= 8u)
                    wsw[(dyi * 9 + d) * 16 + m] = acc[dyi][t][rr];
            }
    __syncthreads();

    const int mm = lane & 15, rg = lane >> 4;
    const size_t ob = (size_t)(b * 81) * HW_ + (size_t)y * W_ + (x0 + mm);
#pragma unroll
    for (int q4 = 0; q4 < 20; ++q4) {
        const int rho = q4 * 4 + rg;
        out[ob + (size_t)rho * HW_] = wsw[rho * 16 + mm];
    }
    if (rg == 0)
        out[ob + (size_t)80 * HW_] = wsw[80 * 16 + mm];
}

extern "C" void kernel_launch(void* const* d_in, const int* in_sizes, int n_in,
                              void* d_out, int out_size, void* d_ws, size_t ws_size,
                              hipStream_t stream) {
    const float* in1 = (const float*)d_in[0];
    const float* in2 = (const float*)d_in[1];
    float* out = (float*)d_out;
    (void)in_sizes; (void)n_in; (void)out_size; (void)ws_size;
    char* in2t = (char*)d_ws;            // 62.9 MB, fits (r8/r11/r12-verified)
    hipLaunchKernelGGL(t2_kernel, dim3(B_ * H_), dim3(256), 0, stream, in2, in2t);
    hipLaunchKernelGGL(corr_mfma6, dim3(NBLK), dim3(512), 0, stream, in1, in2t, out);
}

// Round 14
// 101.012 us; speedup vs baseline: 1.0851x; 1.0003x over previous
//
#include <hip/hip_runtime.h>
#include <stdint.h>

typedef __bf16 bf16;
typedef __attribute__((ext_vector_type(4))) __bf16 bf16x4;
typedef __attribute__((ext_vector_type(8))) __bf16 bf16x8;
typedef __attribute__((ext_vector_type(4))) float f32x4;
typedef __attribute__((ext_vector_type(4))) unsigned int u32x4;

#define W_ 160
#define H_ 96
#define C_ 128
#define B_ 16
#define HW_ (H_ * W_)            // 15360
#define NXT 10                   // 160/16
#define NYB8 12                  // 96/8: 8-row y-bands
#define NBLK (B_ * NYB8 * NXT)   // 1920 = 8*240
#define SLICEB 10240             // in2t bytes per (y,ck) slice: 160x * 4 granules * 16B
#define YB 40960                 // per (b,y): 4 slices
#define ROWSB 1536               // LDS bytes per staged row: 24 xl * 4 granules * 16B
#define CHB (16 * ROWSB)         // 24576 B per chunk (16 halo rows)
#define LDSB (3 * CHB + 512)     // 74240 B: 3 buffers + t=1 overread pad
#define WSSTR 1408               // floats per wave epilogue region (stride 17: 81*17=1377)

__device__ __forceinline__ void g2l16(const void* g, void* l) {
    __builtin_amdgcn_global_load_lds(
        (const __attribute__((address_space(1))) void*)g,
        (__attribute__((address_space(3))) void*)l, 16, 0, 0);
}

// ===== pass 1 (r11-verified): in2 [B][C][H][W] f32 -> in2t granules [b][y][ck][x*4+(g^((x>>1)&3))]
__global__ __launch_bounds__(256) void t2_kernel(const float* __restrict__ in2,
                                                 char* __restrict__ o) {
    __shared__ __align__(16) char T[40960];
    const int L   = blockIdx.x;                     // b*H_ + y
    const int tid = threadIdx.x;
    const float* src = in2 + (size_t)(L / H_) * C_ * HW_ + (size_t)(L % H_) * W_;
    char* dst = o + (size_t)L * YB;
    const float SC = 1.0f / 128.0f;                 // exact fold of 1/(K*K*C)
#pragma unroll
    for (int rd = 0; rd < 5; ++rd) {
        const int s  = rd * 256 + tid;              // 0..1279 = 32 cq x 40 x4
        const int cq = s / 40;
        const int x4 = s - cq * 40;
        const float* p = src + (size_t)(4 * cq) * HW_ + 4 * x4;
        const float4 v0 = *(const float4*)(p);
        const float4 v1 = *(const float4*)(p + HW_);
        const float4 v2 = *(const float4*)(p + 2 * HW_);
        const float4 v3 = *(const float4*)(p + 3 * HW_);
        const int oq = cq >> 1, half = cq & 1;
#pragma unroll
        for (int xj = 0; xj < 4; ++xj) {
            const int x   = 4 * x4 + xj;
            const int pos = oq ^ ((x >> 2) & 15);
            bf16x4 pk;
            pk[0] = (bf16)(((const float*)&v0)[xj] * SC);
            pk[1] = (bf16)(((const float*)&v1)[xj] * SC);
            pk[2] = (bf16)(((const float*)&v2)[xj] * SC);
            pk[3] = (bf16)(((const float*)&v3)[xj] * SC);
            *(bf16x4*)(T + x * 256 + pos * 16 + half * 8) = pk;
        }
    }
    __syncthreads();
#pragma unroll
    for (int wr = 0; wr < 10; ++wr) {
        const int s2  = wr * 256 + tid;
        const int ck  = s2 / 640;
        const int r   = s2 - ck * 640;
        const int x   = r >> 2;
        const int gsw = r & 3;
        const int gg  = gsw ^ ((x >> 1) & 3);
        const int oo  = ck * 4 + gg;
        const int pos = oo ^ ((x >> 2) & 15);
        const u32x4 v = *(const u32x4*)(T + x * 256 + pos * 16);
        *(u32x4*)(dst + (size_t)s2 * 16) = v;
    }
}

// ===== pass 2: 8-wave blocks, 3-buffer depth-2 counted pipeline, reg-dieted, masked epilogue
__global__ __launch_bounds__(512, 4) void corr_mfma7(const float* __restrict__ in1,
                                                     const char* __restrict__ in2t,
                                                     float* __restrict__ out) {
    __shared__ __align__(16) char Bsm[LDSB];        // 74240 B; ws-epilogue reuses

    const int L   = ((int)blockIdx.x & 7) * (NBLK / 8) + ((int)blockIdx.x >> 3);
    const int b   = L / (NYB8 * NXT);
    const int rem = L % (NYB8 * NXT);
    const int yb  = rem / NXT;
    const int xt  = rem % NXT;
    const int x0  = xt * 16, y0 = yb * 8;

    const int tid  = threadIdx.x;
    const int wv   = __builtin_amdgcn_readfirstlane(tid >> 6);  // wave 0..7 -> y row
    const int lane = tid & 63;
    const int n    = lane & 15;          // frag col (A row m / B col)
    const int g    = lane >> 4;          // k-octet
    const int y    = y0 + wv;

    const char* i2tb = in2t + (size_t)b * (H_ * YB);

    // ---- A fragments: per-ck batches of 8, retired before staging ----
    const float* abase = in1 + (size_t)b * C_ * HW_ + (size_t)y * W_ + (x0 + n);
    bf16x8 afrag[4];
#pragma unroll
    for (int ck = 0; ck < 4; ++ck) {
        float ar[8];
#pragma unroll
        for (int j = 0; j < 8; ++j)
            ar[j] = abase[(size_t)(ck * 32 + g * 8 + j) * HW_];
#pragma unroll
        for (int j = 0; j < 8; ++j)
            afrag[ck][j] = (bf16)ar[j];
    }
    asm volatile("s_waitcnt vmcnt(0)" ::: "memory");   // vmcnt now tracks staging only
    __builtin_amdgcn_sched_barrier(0);

    // ---- staging decode: 3 rounds x 512 thr = 1536 slots = 16 rows x 96 granules ----
    // Unconditional clamped loads (LDS fully overwritten each chunk; data always finite);
    // boundary correctness restored by epilogue masks (r8/r10-verified pattern).
    unsigned soff[3];
#pragma unroll
    for (int rd = 0; rd < 3; ++rd) {
        const int slot = rd * 512 + tid;
        const int row  = slot / 96;
        const int sl   = slot - row * 96;
        const int gy   = y0 - 4 + row;
        const int gy_c = min(max(gy, 0), H_ - 1);
        const int ofs  = max((x0 - 4) * 64 + sl * 16, 0);
        soff[rd] = (unsigned)(gy_c * YB + ofs);
    }

    // ---- B-frag read offsets: granule (xl*4 + (g ^ (((x0-4+xl)>>1)&3))) * 16 ----
    int rboff[2];
#pragma unroll
    for (int t = 0; t < 2; ++t) {
        const int xl = n + 16 * t;
        const int sw = g ^ (((xl + 12) >> 1) & 3);   // == ((x0-4+xl)>>1)&3 for x0%16==0
        rboff[t] = (xl * 4 + sw) * 16;
    }

    f32x4 acc[9][2];
#pragma unroll
    for (int dyi = 0; dyi < 9; ++dyi)
#pragma unroll
        for (int t = 0; t < 2; ++t)
            acc[dyi][t] = (f32x4){0.f, 0.f, 0.f, 0.f};

#define STAGE(CK, DST)                                                        \
    {                                                                         \
        const char* bck = i2tb + (CK) * SLICEB;                               \
        _Pragma("unroll")                                                     \
        for (int rd = 0; rd < 3; ++rd)                                        \
            g2l16((const void*)(bck + soff[rd]),                              \
                  (void*)((DST) + (rd * 512 + tid) * 16));                    \
    }
#define WAITB(N)                                                              \
    {                                                                         \
        asm volatile("s_waitcnt vmcnt(" #N ")" ::: "memory");                 \
        __builtin_amdgcn_s_barrier();                                         \
        __builtin_amdgcn_sched_barrier(0);                                    \
    }
#define RBAR                                                                  \
    {                                                                         \
        asm volatile("s_waitcnt lgkmcnt(0)" ::: "memory");                    \
        __builtin_amdgcn_s_barrier();                                         \
        __builtin_amdgcn_sched_barrier(0);                                    \
    }
#define COMPUTE(CK, BUF)                                                      \
    {                                                                         \
        _Pragma("unroll")                                                     \
        for (int dyi = 0; dyi < 9; ++dyi) {                                   \
            const int rowoff = (wv + dyi) * ROWSB;                            \
            _Pragma("unroll")                                                 \
            for (int t = 0; t < 2; ++t) {                                     \
                const bf16x8 bfrag =                                          \
                    *(const bf16x8*)((BUF) + rowoff + rboff[t]);              \
                acc[dyi][t] = __builtin_amdgcn_mfma_f32_16x16x32_bf16(        \
                    afrag[CK], bfrag, acc[dyi][t], 0, 0, 0);                  \
            }                                                                 \
        }                                                                     \
    }

    STAGE(0, Bsm);                 // 3 in flight
    STAGE(1, Bsm + CHB);           // 6
    STAGE(2, Bsm + 2 * CHB);       // 9
    WAITB(6);                      // chunk0 landed (c1,c2 flying)
    COMPUTE(0, Bsm);
    RBAR;                          // all waves done reading B0
    STAGE(3, Bsm);                 // c1,c2,c3 in flight = 9
    WAITB(6);                      // chunk1 landed
    COMPUTE(1, Bsm + CHB);
    WAITB(3);                      // chunk2 landed
    COMPUTE(2, Bsm + 2 * CHB);
    WAITB(0);                      // chunk3 landed
    COMPUTE(3, Bsm);
#undef STAGE
#undef WAITB
#undef RBAR
#undef COMPUTE

    __syncthreads();               // all LDS reads done before ws reuse (C3 read B0)

    // ---- epilogue masks: exact-0 for OOB (x', y') — r8/r10-verified pattern ----
    float xv[2];
#pragma unroll
    for (int t = 0; t < 2; ++t)
        xv[t] = ((unsigned)(x0 - 4 + n + 16 * t) < (unsigned)W_) ? 1.f : 0.f;
    float yv[9];
#pragma unroll
    for (int dyi = 0; dyi < 9; ++dyi)
        yv[dyi] = ((unsigned)(y - 4 + dyi) < (unsigned)H_) ? 1.f : 0.f;

    // ---- epilogue (r7-verified mapping, stride 17, per-wave private: no 2nd barrier) ----
    float* wsw = (float*)Bsm + wv * WSSTR;          // 8*5632 B = 45056 <= 74240
#pragma unroll
    for (int dyi = 0; dyi < 9; ++dyi)
#pragma unroll
        for (int t = 0; t < 2; ++t)
#pragma unroll
            for (int rr = 0; rr < 4; ++rr) {
                const int m = 4 * g + rr;
                const int d = n + 16 * t - m;
                if ((unsigned)d <= 8u)
                    wsw[(dyi * 9 + d) * 17 + m] = acc[dyi][t][rr] * xv[t] * yv[dyi];
            }

    const int mm = lane & 15, rg = lane >> 4;
    const size_t ob = (size_t)(b * 81) * HW_ + (size_t)y * W_ + (x0 + mm);
#pragma unroll
    for (int q4 = 0; q4 < 20; ++q4) {
        const int rho = q4 * 4 + rg;
        out[ob + (size_t)rho * HW_] = wsw[rho * 17 + mm];
    }
    if (rg == 0)
        out[ob + (size_t)80 * HW_] = wsw[80 * 17 + mm];
}

extern "C" void kernel_launch(void* const* d_in, const int* in_sizes, int n_in,
                              void* d_out, int out_size, void* d_ws, size_t ws_size,
                              hipStream_t stream) {
    const float* in1 = (const float*)d_in[0];
    const float* in2 = (const float*)d_in[1];
    float* out = (float*)d_out;
    (void)in_sizes; (void)n_in; (void)out_size; (void)ws_size;
    char* in2t = (char*)d_ws;            // 62.9 MB, fits (r8/r11-r13 verified)
    hipLaunchKernelGGL(t2_kernel, dim3(B_ * H_), dim3(256), 0, stream, in2, in2t);
    hipLaunchKernelGGL(corr_mfma7, dim3(NBLK), dim3(512), 0, stream, in1, in2t, out);
}